// Round 1
// baseline (238.510 us; speedup 1.0000x reference)
//
#include <hip/hip_runtime.h>
#include <math.h>

#define NPTS 65536
#define NS   2048
#define C2   256
#define C3   128

// ---- workspace layout (byte offsets, all 16B aligned) ----
#define WS_XYZ2P   0          // float4[2048]            : 32768 B
#define WS_P2T     32768      // bf16 [2048][256]        : 1048576 B
#define WS_W0F     1081344    // bf16 frag [10][16][64][8] : 163840 B
#define WS_W1F     1245184    // bf16 frag [8][8][64][8]   : 65536 B
#define WS_AB0     1310720    // float A0[256],B0[256]   : 2048 B
#define WS_AB1     1312768    // float A1[128],B1[128]   : 1024 B
#define WS_KIDX    1313792    // int [65536][3]          : 786432 B
#define WS_KW      2100224    // float [65536][3]        : 786432 B
// total: 2886656 B

typedef __attribute__((ext_vector_type(8))) short bf16x8;
typedef __attribute__((ext_vector_type(4))) float f32x4;

__device__ __forceinline__ unsigned short f2bf(float f) {
  unsigned u = __builtin_bit_cast(unsigned, f);
  u = (u + 0x7FFFu + ((u >> 16) & 1u)) >> 16;
  return (unsigned short)u;
}
__device__ __forceinline__ float bf2f(unsigned h) {
  return __builtin_bit_cast(float, h << 16);
}

// =================== prep: pack tables ===================
__global__ __launch_bounds__(256) void pnfp_prep(
    const float* __restrict__ xyz2,
    const float* __restrict__ points2,
    const float* __restrict__ w0, const float* __restrict__ b0,
    const float* __restrict__ scale0, const float* __restrict__ bias0,
    const float* __restrict__ mean0, const float* __restrict__ var0,
    const float* __restrict__ w1, const float* __restrict__ b1,
    const float* __restrict__ scale1, const float* __restrict__ bias1,
    const float* __restrict__ mean1, const float* __restrict__ var1,
    unsigned char* __restrict__ ws)
{
  int gid = blockIdx.x * 256 + threadIdx.x;

  if (gid < 524288) {                 // points2 [256][2048] -> p2t bf16 [2048][256]
    int d = gid >> 11, s = gid & 2047;
    ((unsigned short*)(ws + WS_P2T))[s * 256 + d] = f2bf(points2[d * NS + s]);
    return;
  }
  gid -= 524288;
  if (gid < 2048) {                   // xyz2 pack + |c|^2 (no-fma, numpy order)
    float x = xyz2[gid], y = xyz2[NS + gid], z = xyz2[2 * NS + gid];
    float sc;
    {
#pragma clang fp contract(off)
      sc = (x * x + y * y) + z * z;
    }
    ((float4*)(ws + WS_XYZ2P))[gid] = make_float4(x, y, z, sc);
    return;
  }
  gid -= 2048;
  if (gid < 81920) {                  // W0 -> fragment-linear bf16
    int i = gid & 7, l = (gid >> 3) & 63, c = (gid >> 9) & 15, ks = gid >> 13;
    int k = ks * 32 + (l >> 4) * 8 + i;
    int col = c * 16 + (l & 15);
    ((unsigned short*)(ws + WS_W0F))[gid] = f2bf(w0[k * C2 + col]);
    return;
  }
  gid -= 81920;
  if (gid < 32768) {                  // W1 -> fragment-linear bf16
    int i = gid & 7, l = (gid >> 3) & 63, c = (gid >> 9) & 7, ks = gid >> 12;
    int k = ks * 32 + (l >> 4) * 8 + i;
    int col = c * 16 + (l & 15);
    ((unsigned short*)(ws + WS_W1F))[gid] = f2bf(w1[k * C3 + col]);
    return;
  }
  gid -= 32768;
  if (gid < 256) {                    // fused conv-bias + BN affine, layer 0
    float a = scale0[gid] / sqrtf(var0[gid] + 1e-5f);
    float bb = (b0[gid] - mean0[gid]) * a + bias0[gid];
    float* ab = (float*)(ws + WS_AB0);
    ab[gid] = a; ab[256 + gid] = bb;
    return;
  }
  gid -= 256;
  if (gid < 128) {                    // layer 1
    float a = scale1[gid] / sqrtf(var1[gid] + 1e-5f);
    float bb = (b1[gid] - mean1[gid]) * a + bias1[gid];
    float* ab = (float*)(ws + WS_AB1);
    ab[gid] = a; ab[128 + gid] = bb;
  }
}

// =================== KNN: top-3 of 2048 per point ===================
// 2 threads per point (one per centre-half), shfl merge. Distance formula
// mirrors numpy: d = (|x|^2 + |c|^2) - 2*dot, dot as BLAS-style fma chain.
__global__ __launch_bounds__(256) void pnfp_knn(
    const float* __restrict__ xyz1, unsigned char* __restrict__ ws)
{
  __shared__ float4 cs[NS];
  const float4* c4 = (const float4*)(ws + WS_XYZ2P);
  for (int j = threadIdx.x; j < NS; j += 256) cs[j] = c4[j];
  __syncthreads();

  const int tid = threadIdx.x;
  const int half = tid & 1;
  const int n = blockIdx.x * 128 + (tid >> 1);
  const float x = xyz1[n], y = xyz1[NPTS + n], z = xyz1[2 * NPTS + n];
  float sx;
  {
#pragma clang fp contract(off)
    sx = (x * x + y * y) + z * z;
  }
  float d0 = 1e30f, d1 = 1e30f, d2 = 1e30f;
  int i0 = 0, i1 = 0, i2 = 0;
  const int sbase = half << 10;
#pragma unroll 4
  for (int t = 0; t < 1024; ++t) {
    const int s = sbase + t;
    float4 c = cs[s];
    float dot = fmaf(z, c.z, fmaf(y, c.y, x * c.x));
    float d = (sx + c.w) - 2.0f * dot;
    if (d < d2) {
      const bool lt1 = d < d1, lt0 = d < d0;
      d2 = lt1 ? d1 : d;  i2 = lt1 ? i1 : s;
      d1 = lt0 ? d0 : (lt1 ? d : d1);
      i1 = lt0 ? i0 : (lt1 ? s : i1);
      d0 = lt0 ? d : d0;  i0 = lt0 ? s : i0;
    }
  }
  // merge partner half's sorted triple (ties keep own list; only half==0 writes,
  // and for half==0 "own" is the lower-index half -> matches top_k tie rule)
  float e0 = __shfl_xor(d0, 1), e1 = __shfl_xor(d1, 1), e2 = __shfl_xor(d2, 1);
  int  j0 = __shfl_xor(i0, 1), j1 = __shfl_xor(i1, 1), j2 = __shfl_xor(i2, 1);

  bool t0 = e0 < d0;
  float r0 = t0 ? e0 : d0; int ri0 = t0 ? j0 : i0;
  float X0 = t0 ? d0 : d1,  X1 = t0 ? d1 : d2;
  int  XI0 = t0 ? i0 : i1, XI1 = t0 ? i1 : i2;
  float Y0 = t0 ? e1 : e0,  Yv1 = t0 ? e2 : e1;
  int  YJ0 = t0 ? j1 : j0, YJ1 = t0 ? j2 : j1;
  bool t1 = Y0 < X0;
  float r1 = t1 ? Y0 : X0; int ri1 = t1 ? YJ0 : XI0;
  float X0b = t1 ? X0 : X1; int XI0b = t1 ? XI0 : XI1;
  float Y0b = t1 ? Yv1 : Y0; int YJ0b = t1 ? YJ1 : YJ0;
  bool t2 = Y0b < X0b;
  float r2 = t2 ? Y0b : X0b; int ri2 = t2 ? YJ0b : XI0b;

  if (half == 0) {
    float q0 = 1.0f / (r0 + 1e-8f);
    float q1 = 1.0f / (r1 + 1e-8f);
    float q2 = 1.0f / (r2 + 1e-8f);
    float qs = (q0 + q1) + q2;
    int* oi = (int*)(ws + WS_KIDX) + 3 * n;
    float* owp = (float*)(ws + WS_KW) + 3 * n;
    oi[0] = ri0; oi[1] = ri1; oi[2] = ri2;
    owp[0] = q0 / qs; owp[1] = q1 / qs; owp[2] = q2 / qs;
  }
}

// =================== fused interp + concat + MLP ===================
// BM=64 points/block, 256 threads (4 waves). Wave w owns output-column strip.
// F tile [64][328] bf16 in LDS (stride 328 => 2-way-only bank aliasing),
// B-fragments streamed from L2-resident fragment-packed weights.
__global__ __launch_bounds__(256, 3) void pnfp_fused(
    const float* __restrict__ points1,
    const unsigned char* __restrict__ ws,
    float* __restrict__ out)
{
  __shared__ __align__(16) unsigned char smem[41984];
  unsigned short* Fh = (unsigned short*)smem;                 // [64][328] bf16
  const unsigned short* p2t = (const unsigned short*)(ws + WS_P2T);
  const unsigned short* w0f = (const unsigned short*)(ws + WS_W0F);
  const unsigned short* w1f = (const unsigned short*)(ws + WS_W1F);
  const float* ab0 = (const float*)(ws + WS_AB0);
  const float* ab1 = (const float*)(ws + WS_AB1);
  const int* kidx = (const int*)(ws + WS_KIDX);
  const float* kw = (const float*)(ws + WS_KW);

  const int tid = threadIdx.x;
  const int wv = tid >> 6, lane = tid & 63;
  const int n0 = blockIdx.x * 64;

  // ---- F part 1: points1^T (cols 0..63)
#pragma unroll
  for (int it = 0; it < 16; ++it) {
    int j = tid + it * 256;
    int d = j >> 6, r = j & 63;
    Fh[r * 328 + d] = f2bf(points1[d * NPTS + n0 + r]);
  }
  // ---- F part 2: 3-NN weighted interpolation (cols 64..319)
  {
    const int dbase = lane * 4;
    for (int rr = 0; rr < 16; ++rr) {
      const int r = wv * 16 + rr, n = n0 + r;
      const int a0 = kidx[3 * n], a1 = kidx[3 * n + 1], a2 = kidx[3 * n + 2];
      const float w0 = kw[3 * n], w1 = kw[3 * n + 1], w2 = kw[3 * n + 2];
      uint2 u0 = *(const uint2*)(p2t + a0 * 256 + dbase);
      uint2 u1 = *(const uint2*)(p2t + a1 * 256 + dbase);
      uint2 u2 = *(const uint2*)(p2t + a2 * 256 + dbase);
      float f0 = fmaf(w2, bf2f(u2.x & 0xFFFFu), fmaf(w1, bf2f(u1.x & 0xFFFFu), w0 * bf2f(u0.x & 0xFFFFu)));
      float f1 = fmaf(w2, bf2f(u2.x >> 16),     fmaf(w1, bf2f(u1.x >> 16),     w0 * bf2f(u0.x >> 16)));
      float f2v = fmaf(w2, bf2f(u2.y & 0xFFFFu), fmaf(w1, bf2f(u1.y & 0xFFFFu), w0 * bf2f(u0.y & 0xFFFFu)));
      float f3 = fmaf(w2, bf2f(u2.y >> 16),     fmaf(w1, bf2f(u1.y >> 16),     w0 * bf2f(u0.y >> 16)));
      uint2 pk;
      pk.x = (unsigned)f2bf(f0) | ((unsigned)f2bf(f1) << 16);
      pk.y = (unsigned)f2bf(f2v) | ((unsigned)f2bf(f3) << 16);
      *(uint2*)(Fh + r * 328 + 64 + dbase) = pk;
    }
  }
  __syncthreads();

  // ---- GEMM1: [64,320] x [320,256], wave w -> cols [w*64, w*64+64)
  f32x4 zero4 = {0.f, 0.f, 0.f, 0.f};
  f32x4 acc[4][4];
#pragma unroll
  for (int a = 0; a < 4; ++a)
#pragma unroll
    for (int b = 0; b < 4; ++b) acc[a][b] = zero4;

  const int arow = lane & 15;
  const int koff = (lane >> 4) * 8;
  for (int ks = 0; ks < 10; ++ks) {
    bf16x8 af[4];
#pragma unroll
    for (int rt = 0; rt < 4; ++rt)
      af[rt] = *(const bf16x8*)(Fh + (rt * 16 + arow) * 328 + ks * 32 + koff);
#pragma unroll
    for (int ct = 0; ct < 4; ++ct) {
      bf16x8 bfv = *(const bf16x8*)(w0f + ((ks * 16 + wv * 4 + ct) * 64 + lane) * 8);
#pragma unroll
      for (int rt = 0; rt < 4; ++rt)
        acc[rt][ct] = __builtin_amdgcn_mfma_f32_16x16x32_bf16(af[rt], bfv, acc[rt][ct], 0, 0, 0);
    }
  }
  __syncthreads();

  // ---- BN+ReLU -> Y1 bf16 [64][264] (reuses smem)
  unsigned short* Y1 = (unsigned short*)smem;
#pragma unroll
  for (int ct = 0; ct < 4; ++ct) {
    const int c = wv * 64 + ct * 16 + arow;
    const float a = ab0[c], b = ab0[256 + c];
#pragma unroll
    for (int rt = 0; rt < 4; ++rt) {
      const int rbase = rt * 16 + (lane >> 4) * 4;
#pragma unroll
      for (int q = 0; q < 4; ++q) {
        float yv = fmaxf(fmaf(acc[rt][ct][q], a, b), 0.0f);
        Y1[(rbase + q) * 264 + c] = f2bf(yv);
      }
    }
  }
  __syncthreads();

  // ---- GEMM2: [64,256] x [256,128], wave w -> cols [w*32, w*32+32)
  f32x4 acc2[4][2];
#pragma unroll
  for (int a = 0; a < 4; ++a) { acc2[a][0] = zero4; acc2[a][1] = zero4; }
  for (int ks = 0; ks < 8; ++ks) {
    bf16x8 af[4];
#pragma unroll
    for (int rt = 0; rt < 4; ++rt)
      af[rt] = *(const bf16x8*)(Y1 + (rt * 16 + arow) * 264 + ks * 32 + koff);
#pragma unroll
    for (int ct = 0; ct < 2; ++ct) {
      bf16x8 bfv = *(const bf16x8*)(w1f + ((ks * 8 + wv * 2 + ct) * 64 + lane) * 8);
#pragma unroll
      for (int rt = 0; rt < 4; ++rt)
        acc2[rt][ct] = __builtin_amdgcn_mfma_f32_16x16x32_bf16(af[rt], bfv, acc2[rt][ct], 0, 0, 0);
    }
  }
  __syncthreads();

  // ---- BN+ReLU -> OUT f32 [128][66] in LDS, then coalesced global store
  float* OUT = (float*)smem;
#pragma unroll
  for (int ct = 0; ct < 2; ++ct) {
    const int c = wv * 32 + ct * 16 + arow;
    const float a = ab1[c], b = ab1[128 + c];
#pragma unroll
    for (int rt = 0; rt < 4; ++rt) {
      const int rbase = rt * 16 + (lane >> 4) * 4;
#pragma unroll
      for (int q = 0; q < 4; ++q)
        OUT[c * 66 + rbase + q] = fmaxf(fmaf(acc2[rt][ct][q], a, b), 0.0f);
    }
  }
  __syncthreads();
#pragma unroll
  for (int it = 0; it < 32; ++it) {
    int j = tid + it * 256;
    int c = j >> 6, n = j & 63;
    out[c * NPTS + n0 + n] = OUT[c * 66 + n];
  }
}

// =================== host launcher ===================
extern "C" void kernel_launch(void* const* d_in, const int* in_sizes, int n_in,
                              void* d_out, int out_size, void* d_ws, size_t ws_size,
                              hipStream_t stream) {
  (void)in_sizes; (void)n_in; (void)out_size; (void)ws_size;
  const float* xyz1    = (const float*)d_in[0];
  const float* xyz2    = (const float*)d_in[1];
  const float* points1 = (const float*)d_in[2];
  const float* points2 = (const float*)d_in[3];
  const float* w0      = (const float*)d_in[4];
  const float* b0      = (const float*)d_in[5];
  const float* scale0  = (const float*)d_in[6];
  const float* bias0   = (const float*)d_in[7];
  const float* mean0   = (const float*)d_in[8];
  const float* var0    = (const float*)d_in[9];
  const float* w1      = (const float*)d_in[10];
  const float* b1      = (const float*)d_in[11];
  const float* scale1  = (const float*)d_in[12];
  const float* bias1   = (const float*)d_in[13];
  const float* mean1   = (const float*)d_in[14];
  const float* var1    = (const float*)d_in[15];
  unsigned char* ws = (unsigned char*)d_ws;
  float* out = (float*)d_out;

  pnfp_prep<<<2506, 256, 0, stream>>>(xyz2, points2, w0, b0, scale0, bias0, mean0, var0,
                                      w1, b1, scale1, bias1, mean1, var1, ws);
  pnfp_knn<<<512, 256, 0, stream>>>(xyz1, ws);
  pnfp_fused<<<1024, 256, 0, stream>>>(points1, ws, out);
}

// Round 3
// 190.099 us; speedup vs baseline: 1.2547x; 1.2547x over previous
//
#include <hip/hip_runtime.h>
#include <math.h>

#define NPTS 65536
#define NS   2048
#define C2   256
#define C3   128

// ---- workspace layout (byte offsets, all 16B aligned) ----
#define WS_XYZ2P   0          // float4[2048]            : 32768 B
#define WS_P2T     32768      // bf16 [2048][256]        : 1048576 B
#define WS_W0F     1081344    // bf16 frag [10][16][64][8] : 163840 B
#define WS_W1F     1245184    // bf16 frag [8][8][64][8]   : 65536 B
#define WS_AB0     1310720    // float A0[256],B0[256]   : 2048 B
#define WS_AB1     1312768    // float A1[128],B1[128]   : 1024 B
#define WS_KIDX    1313792    // int [65536][3]          : 786432 B
#define WS_KW      2100224    // float [65536][3]        : 786432 B
// total: 2886656 B

typedef __attribute__((ext_vector_type(8))) short bf16x8;
typedef __attribute__((ext_vector_type(4))) float f32x4;

__device__ __forceinline__ unsigned short f2bf(float f) {
  unsigned u = __builtin_bit_cast(unsigned, f);
  u = (u + 0x7FFFu + ((u >> 16) & 1u)) >> 16;
  return (unsigned short)u;
}
__device__ __forceinline__ float bf2f(unsigned h) {
  return __builtin_bit_cast(float, h << 16);
}

// =================== prep: pack tables (no transpose here) ===================
__global__ __launch_bounds__(256) void pnfp_prep(
    const float* __restrict__ xyz2,
    const float* __restrict__ w0, const float* __restrict__ b0,
    const float* __restrict__ scale0, const float* __restrict__ bias0,
    const float* __restrict__ mean0, const float* __restrict__ var0,
    const float* __restrict__ w1, const float* __restrict__ b1,
    const float* __restrict__ scale1, const float* __restrict__ bias1,
    const float* __restrict__ mean1, const float* __restrict__ var1,
    unsigned char* __restrict__ ws)
{
  int gid = blockIdx.x * 256 + threadIdx.x;

  if (gid < 2048) {                   // xyz2 pack + |c|^2 (no-fma, numpy order)
    float x = xyz2[gid], y = xyz2[NS + gid], z = xyz2[2 * NS + gid];
    float sc;
    {
#pragma clang fp contract(off)
      sc = (x * x + y * y) + z * z;
    }
    ((float4*)(ws + WS_XYZ2P))[gid] = make_float4(x, y, z, sc);
    return;
  }
  gid -= 2048;
  if (gid < 81920) {                  // W0 -> fragment-linear bf16
    int i = gid & 7, l = (gid >> 3) & 63, c = (gid >> 9) & 15, ks = gid >> 13;
    int k = ks * 32 + (l >> 4) * 8 + i;
    int col = c * 16 + (l & 15);
    ((unsigned short*)(ws + WS_W0F))[gid] = f2bf(w0[k * C2 + col]);
    return;
  }
  gid -= 81920;
  if (gid < 32768) {                  // W1 -> fragment-linear bf16
    int i = gid & 7, l = (gid >> 3) & 63, c = (gid >> 9) & 7, ks = gid >> 12;
    int k = ks * 32 + (l >> 4) * 8 + i;
    int col = c * 16 + (l & 15);
    ((unsigned short*)(ws + WS_W1F))[gid] = f2bf(w1[k * C3 + col]);
    return;
  }
  gid -= 32768;
  if (gid < 256) {                    // fused conv-bias + BN affine, layer 0
    float a = scale0[gid] / sqrtf(var0[gid] + 1e-5f);
    float bb = (b0[gid] - mean0[gid]) * a + bias0[gid];
    float* ab = (float*)(ws + WS_AB0);
    ab[gid] = a; ab[256 + gid] = bb;
    return;
  }
  gid -= 256;
  if (gid < 128) {                    // layer 1
    float a = scale1[gid] / sqrtf(var1[gid] + 1e-5f);
    float bb = (b1[gid] - mean1[gid]) * a + bias1[gid];
    float* ab = (float*)(ws + WS_AB1);
    ab[gid] = a; ab[128 + gid] = bb;
  }
}

// =================== transpose points2 [256][2048]f32 -> [2048][256]bf16 ===================
// LDS-tiled 64x64: coalesced 256B global reads, contiguous 128B global writes.
__global__ __launch_bounds__(256) void pnfp_tpose(
    const float* __restrict__ points2, unsigned char* __restrict__ ws)
{
  __shared__ float tile[64][65];      // pad 65: bank = (d+s)%32, 2-way max
  const int st = blockIdx.x & 31;     // s-tile (2048/64)
  const int dt = blockIdx.x >> 5;     // d-tile (256/64)
  const int tid = threadIdx.x;
#pragma unroll
  for (int it = 0; it < 16; ++it) {
    int j = it * 256 + tid;
    int d = j >> 6, s = j & 63;
    tile[d][s] = points2[(dt * 64 + d) * NS + st * 64 + s];
  }
  __syncthreads();
  unsigned short* p2t = (unsigned short*)(ws + WS_P2T);
#pragma unroll
  for (int it = 0; it < 16; ++it) {
    int j = it * 256 + tid;
    int s = j >> 6, d = j & 63;
    p2t[(st * 64 + s) * 256 + dt * 64 + d] = f2bf(tile[d][s]);
  }
}

// =================== KNN: top-3 of 2048 per point ===================
// 4 threads per point (one per centre quarter), 2-stage shfl merge.
// LDS quarters padded by one float4 -> 4 distinct bank groups, conflict-free.
// Distance mirrors numpy: d = (|x|^2 + |c|^2) - 2*dot, dot as fma chain.
__global__ __launch_bounds__(256) void pnfp_knn(
    const float* __restrict__ xyz1, unsigned char* __restrict__ ws)
{
  __shared__ float4 cs[4 * 513];
  const float4* c4 = (const float4*)(ws + WS_XYZ2P);
  for (int j = threadIdx.x; j < NS; j += 256) {
    int qq = j >> 9, tt = j & 511;
    cs[qq * 513 + tt] = c4[j];
  }
  __syncthreads();

  const int tid = threadIdx.x;
  const int q = tid & 3;                       // centre-quarter (even lanes own lower idx)
  const int n = blockIdx.x * 64 + (tid >> 2);
  const float x = xyz1[n], y = xyz1[NPTS + n], z = xyz1[2 * NPTS + n];
  float sx;
  {
#pragma clang fp contract(off)
    sx = (x * x + y * y) + z * z;
  }
  float d0 = 1e30f, d1 = 1e30f, d2 = 1e30f;
  int i0 = 0, i1 = 0, i2 = 0;
  const float4* cq = cs + q * 513;
  const int sbase = q << 9;
#pragma unroll 8
  for (int t = 0; t < 512; ++t) {
    float4 c = cq[t];
    float dot = fmaf(z, c.z, fmaf(y, c.y, x * c.x));
    float d = (sx + c.w) - 2.0f * dot;
    if (d < d2) {                              // rare (E[hits] ~ O(log))
      const bool lt1 = d < d1, lt0 = d < d0;
      const int s = sbase + t;
      d2 = lt1 ? d1 : d;  i2 = lt1 ? i1 : s;
      d1 = lt0 ? d0 : (lt1 ? d : d1);
      i1 = lt0 ? i0 : (lt1 ? s : i1);
      d0 = lt0 ? d : d0;  i0 = lt0 ? s : i0;
    }
  }
  // two merge stages (xor 1, then xor 2). Strict '<' prefers OWN list on ties;
  // lanes whose results are consumed (q=0 at both stages, q=2 at stage 1) always
  // own the lower-index range -> matches numpy top_k tie rule.
#pragma unroll
  for (int m = 1; m <= 2; m <<= 1) {
    float e0 = __shfl_xor(d0, m), e1 = __shfl_xor(d1, m), e2 = __shfl_xor(d2, m);
    int  j0 = __shfl_xor(i0, m), j1 = __shfl_xor(i1, m), j2 = __shfl_xor(i2, m);
    bool t0 = e0 < d0;
    float r0 = t0 ? e0 : d0; int ri0 = t0 ? j0 : i0;
    float X0 = t0 ? d0 : d1,  X1 = t0 ? d1 : d2;
    int  XI0 = t0 ? i0 : i1, XI1 = t0 ? i1 : i2;
    float Y0 = t0 ? e1 : e0,  Y1v = t0 ? e2 : e1;
    int  YJ0 = t0 ? j1 : j0, YJ1 = t0 ? j2 : j1;
    bool t1 = Y0 < X0;
    float r1 = t1 ? Y0 : X0; int ri1 = t1 ? YJ0 : XI0;
    float X0b = t1 ? X0 : X1; int XI0b = t1 ? XI0 : XI1;
    float Y0b = t1 ? Y1v : Y0; int YJ0b = t1 ? YJ1 : YJ0;
    bool t2 = Y0b < X0b;
    float r2 = t2 ? Y0b : X0b; int ri2 = t2 ? YJ0b : XI0b;
    d0 = r0; d1 = r1; d2 = r2; i0 = ri0; i1 = ri1; i2 = ri2;
  }

  if (q == 0) {
    float q0 = 1.0f / (d0 + 1e-8f);
    float q1 = 1.0f / (d1 + 1e-8f);
    float q2 = 1.0f / (d2 + 1e-8f);
    float qs = (q0 + q1) + q2;
    int* oi = (int*)(ws + WS_KIDX) + 3 * n;
    float* owp = (float*)(ws + WS_KW) + 3 * n;
    oi[0] = i0; oi[1] = i1; oi[2] = i2;
    owp[0] = q0 / qs; owp[1] = q1 / qs; owp[2] = q2 / qs;
  }
}

// =================== fused interp + concat + MLP ===================
// BM=64 points/block, 256 threads (4 waves). Wave w owns output-column strip.
// F tile [64][328] bf16 in LDS (stride/8 odd => uniform 8x8 bank spread on b128),
// B-fragments streamed from L2-resident packed weights with next-K prefetch.
__global__ __launch_bounds__(256, 3) void pnfp_fused(
    const float* __restrict__ points1,
    const unsigned char* __restrict__ ws,
    float* __restrict__ out)
{
  __shared__ __align__(16) unsigned char smem[41984];
  unsigned short* Fh = (unsigned short*)smem;                 // [64][328] bf16
  const unsigned short* p2t = (const unsigned short*)(ws + WS_P2T);
  const unsigned short* w0f = (const unsigned short*)(ws + WS_W0F);
  const unsigned short* w1f = (const unsigned short*)(ws + WS_W1F);
  const float* ab0 = (const float*)(ws + WS_AB0);
  const float* ab1 = (const float*)(ws + WS_AB1);
  const int* kidx = (const int*)(ws + WS_KIDX);
  const float* kw = (const float*)(ws + WS_KW);

  const int tid = threadIdx.x;
  const int wv = tid >> 6, lane = tid & 63;
  const int n0 = blockIdx.x * 64;

  // ---- F part 1: points1^T (cols 0..63)
#pragma unroll
  for (int it = 0; it < 16; ++it) {
    int j = tid + it * 256;
    int d = j >> 6, r = j & 63;
    Fh[r * 328 + d] = f2bf(points1[d * NPTS + n0 + r]);
  }
  // ---- F part 2: 3-NN weighted interpolation (cols 64..319)
  {
    const int dbase = lane * 4;
#pragma unroll 2
    for (int rr = 0; rr < 16; ++rr) {
      const int r = wv * 16 + rr, n = n0 + r;
      const int a0 = kidx[3 * n], a1 = kidx[3 * n + 1], a2 = kidx[3 * n + 2];
      const float w0 = kw[3 * n], w1 = kw[3 * n + 1], w2 = kw[3 * n + 2];
      uint2 u0 = *(const uint2*)(p2t + a0 * 256 + dbase);
      uint2 u1 = *(const uint2*)(p2t + a1 * 256 + dbase);
      uint2 u2 = *(const uint2*)(p2t + a2 * 256 + dbase);
      float f0 = fmaf(w2, bf2f(u2.x & 0xFFFFu), fmaf(w1, bf2f(u1.x & 0xFFFFu), w0 * bf2f(u0.x & 0xFFFFu)));
      float f1 = fmaf(w2, bf2f(u2.x >> 16),     fmaf(w1, bf2f(u1.x >> 16),     w0 * bf2f(u0.x >> 16)));
      float f2v = fmaf(w2, bf2f(u2.y & 0xFFFFu), fmaf(w1, bf2f(u1.y & 0xFFFFu), w0 * bf2f(u0.y & 0xFFFFu)));
      float f3 = fmaf(w2, bf2f(u2.y >> 16),     fmaf(w1, bf2f(u1.y >> 16),     w0 * bf2f(u0.y >> 16)));
      uint2 pk;
      pk.x = (unsigned)f2bf(f0) | ((unsigned)f2bf(f1) << 16);
      pk.y = (unsigned)f2bf(f2v) | ((unsigned)f2bf(f3) << 16);
      *(uint2*)(Fh + r * 328 + 64 + dbase) = pk;
    }
  }
  __syncthreads();

  // ---- GEMM1: [64,320] x [320,256], wave w -> cols [w*64, w*64+64)
  f32x4 zero4 = {0.f, 0.f, 0.f, 0.f};
  f32x4 acc[4][4];
#pragma unroll
  for (int a = 0; a < 4; ++a)
#pragma unroll
    for (int b = 0; b < 4; ++b) acc[a][b] = zero4;

  const int arow = lane & 15;
  const int koff = (lane >> 4) * 8;
  bf16x8 bcur[4], bnxt[4];
#pragma unroll
  for (int ct = 0; ct < 4; ++ct)
    bcur[ct] = *(const bf16x8*)(w0f + ((wv * 4 + ct) * 64 + lane) * 8);
  for (int ks = 0; ks < 10; ++ks) {
    // prefetch next K-step's B fragments (ks=9 reads into W1F region: in-bounds, unused)
#pragma unroll
    for (int ct = 0; ct < 4; ++ct)
      bnxt[ct] = *(const bf16x8*)(w0f + (((ks + 1) * 16 + wv * 4 + ct) * 64 + lane) * 8);
    bf16x8 af[4];
#pragma unroll
    for (int rt = 0; rt < 4; ++rt)
      af[rt] = *(const bf16x8*)(Fh + (rt * 16 + arow) * 328 + ks * 32 + koff);
#pragma unroll
    for (int ct = 0; ct < 4; ++ct)
#pragma unroll
      for (int rt = 0; rt < 4; ++rt)
        acc[rt][ct] = __builtin_amdgcn_mfma_f32_16x16x32_bf16(af[rt], bcur[ct], acc[rt][ct], 0, 0, 0);
#pragma unroll
    for (int ct = 0; ct < 4; ++ct) bcur[ct] = bnxt[ct];
  }
  __syncthreads();

  // ---- BN+ReLU -> Y1 bf16 [64][264] (reuses smem)
  unsigned short* Y1 = (unsigned short*)smem;
#pragma unroll
  for (int ct = 0; ct < 4; ++ct) {
    const int c = wv * 64 + ct * 16 + arow;
    const float a = ab0[c], b = ab0[256 + c];
#pragma unroll
    for (int rt = 0; rt < 4; ++rt) {
      const int rbase = rt * 16 + (lane >> 4) * 4;
#pragma unroll
      for (int qi = 0; qi < 4; ++qi) {
        float yv = fmaxf(fmaf(acc[rt][ct][qi], a, b), 0.0f);
        Y1[(rbase + qi) * 264 + c] = f2bf(yv);
      }
    }
  }
  __syncthreads();

  // ---- GEMM2: [64,256] x [256,128], wave w -> cols [w*32, w*32+32)
  f32x4 acc2[4][2];
#pragma unroll
  for (int a = 0; a < 4; ++a) { acc2[a][0] = zero4; acc2[a][1] = zero4; }
  bf16x8 b2cur[2], b2nxt[2];
#pragma unroll
  for (int ct = 0; ct < 2; ++ct)
    b2cur[ct] = *(const bf16x8*)(w1f + ((wv * 2 + ct) * 64 + lane) * 8);
  for (int ks = 0; ks < 8; ++ks) {
#pragma unroll
    for (int ct = 0; ct < 2; ++ct)
      b2nxt[ct] = *(const bf16x8*)(w1f + (((ks + 1) * 8 + wv * 2 + ct) * 64 + lane) * 8);
    bf16x8 af[4];
#pragma unroll
    for (int rt = 0; rt < 4; ++rt)
      af[rt] = *(const bf16x8*)(Y1 + (rt * 16 + arow) * 264 + ks * 32 + koff);
#pragma unroll
    for (int ct = 0; ct < 2; ++ct)
#pragma unroll
      for (int rt = 0; rt < 4; ++rt)
        acc2[rt][ct] = __builtin_amdgcn_mfma_f32_16x16x32_bf16(af[rt], b2cur[ct], acc2[rt][ct], 0, 0, 0);
#pragma unroll
    for (int ct = 0; ct < 2; ++ct) b2cur[ct] = b2nxt[ct];
  }
  __syncthreads();

  // ---- BN+ReLU -> OUT f32 [128][67] in LDS, then coalesced global store
  float* OUT = (float*)smem;
#pragma unroll
  for (int ct = 0; ct < 2; ++ct) {
    const int c = wv * 32 + ct * 16 + arow;
    const float a = ab1[c], b = ab1[128 + c];
#pragma unroll
    for (int rt = 0; rt < 4; ++rt) {
      const int rbase = rt * 16 + (lane >> 4) * 4;
#pragma unroll
      for (int qi = 0; qi < 4; ++qi)
        OUT[c * 67 + rbase + qi] = fmaxf(fmaf(acc2[rt][ct][qi], a, b), 0.0f);
    }
  }
  __syncthreads();
#pragma unroll
  for (int it = 0; it < 32; ++it) {
    int j = tid + it * 256;
    int c = j >> 6, n = j & 63;
    out[c * NPTS + n0 + n] = OUT[c * 67 + n];
  }
}

// =================== host launcher ===================
extern "C" void kernel_launch(void* const* d_in, const int* in_sizes, int n_in,
                              void* d_out, int out_size, void* d_ws, size_t ws_size,
                              hipStream_t stream) {
  (void)in_sizes; (void)n_in; (void)out_size; (void)ws_size;
  const float* xyz1    = (const float*)d_in[0];
  const float* xyz2    = (const float*)d_in[1];
  const float* points1 = (const float*)d_in[2];
  const float* points2 = (const float*)d_in[3];
  const float* w0      = (const float*)d_in[4];
  const float* b0      = (const float*)d_in[5];
  const float* scale0  = (const float*)d_in[6];
  const float* bias0   = (const float*)d_in[7];
  const float* mean0   = (const float*)d_in[8];
  const float* var0    = (const float*)d_in[9];
  const float* w1      = (const float*)d_in[10];
  const float* b1      = (const float*)d_in[11];
  const float* scale1  = (const float*)d_in[12];
  const float* bias1   = (const float*)d_in[13];
  const float* mean1   = (const float*)d_in[14];
  const float* var1    = (const float*)d_in[15];
  unsigned char* ws = (unsigned char*)d_ws;
  float* out = (float*)d_out;

  pnfp_prep<<<458, 256, 0, stream>>>(xyz2, w0, b0, scale0, bias0, mean0, var0,
                                     w1, b1, scale1, bias1, mean1, var1, ws);
  pnfp_tpose<<<128, 256, 0, stream>>>(points2, ws);
  pnfp_knn<<<1024, 256, 0, stream>>>(xyz1, ws);
  pnfp_fused<<<1024, 256, 0, stream>>>(points1, ws, out);
}